// Round 10
// baseline (334.277 us; speedup 1.0000x reference)
//
#include <hip/hip_runtime.h>
#include <hip/hip_bf16.h>
#include <cstdint>
#include <cstddef>

#define AS1 __attribute__((address_space(1)))
#define AS3 __attribute__((address_space(3)))

typedef __bf16 bf16x8  __attribute__((ext_vector_type(8)));
typedef __bf16 bf16x4  __attribute__((ext_vector_type(4)));
typedef float  floatx4 __attribute__((ext_vector_type(4)));
typedef float  floatx16 __attribute__((ext_vector_type(16)));

__device__ __forceinline__ void load_lds16(const void* g, void* l) {
    __builtin_amdgcn_global_load_lds((AS1 void*)g, (AS3 void*)l, 16, 0, 0);
}

__device__ __forceinline__ float fexp2(float x) { return __builtin_amdgcn_exp2f(x); }
__device__ __forceinline__ float flog2(float x) { return __builtin_amdgcn_logf(x); }

#define LOG2E 1.4426950408889634f
#define LN2   0.6931471805599453f
#define C0K   2.3052328943245633f   /* 0.5*log(2pi) + log(4) */

__device__ __forceinline__ float logp2(float xv, float mu, float al) {
    float e = fexp2(-al * LOG2E);
    float z = (xv - mu) * e;
    return (-0.5f * z * z - al - C0K) * LOG2E;
}
__device__ __forceinline__ float lse4(float a0, float a1, float a2, float a3) {
    float mx = fmaxf(fmaxf(a0, a1), fmaxf(a2, a3));
    return mx + flog2(fexp2(a0 - mx) + fexp2(a1 - mx) +
                      fexp2(a2 - mx) + fexp2(a3 - mx));
}
__device__ __forceinline__ void lmm4(const float* Aa, const float* Bb, float* D) {
#pragma unroll
    for (int r = 0; r < 4; ++r)
#pragma unroll
        for (int c = 0; c < 4; ++c)
            D[r * 4 + c] = lse4(Aa[r * 4 + 0] + Bb[0 * 4 + c],
                                Aa[r * 4 + 1] + Bb[1 * 4 + c],
                                Aa[r * 4 + 2] + Bb[2 * 4 + c],
                                Aa[r * 4 + 3] + Bb[3 * 4 + c]);
}

// EXACT degree sort of the 2048 hidden features, deg(f) = f % 127.
__device__ __forceinline__ int resp_s(int p) {
    return p < 272 ? p / 17 : 16 + ((p - 272) >> 4);
}
__device__ __forceinline__ int invp_s(int p) {
    if (p < 272) { int d = p / 17; int r = p - d * 17;
                   return r < 16 ? d + r * 127 : 2032 + d; }
    int d = 16 + ((p - 272) >> 4); int j = (p - 272) & 15;
    return d + j * 127;
}
__device__ __forceinline__ int cnt_le(int D) {
    return D < 16 ? (D + 1) * 17 : 272 + ((D - 15) << 4);
}

// ---------------------------------------------------------------------------
// Prep: masks + fp32->bf16 + exact degree-sort, coalesced both sides via LDS.
// ---------------------------------------------------------------------------
__global__ __launch_bounds__(256)
void prep_all(const float* __restrict__ x,  const float* __restrict__ W0,
              const float* __restrict__ W1, const float* __restrict__ W2,
              const float* __restrict__ W3,
              __bf16* __restrict__ xb,  __bf16* __restrict__ w0m,
              __bf16* __restrict__ w1m, __bf16* __restrict__ w2m,
              __bf16* __restrict__ w3m)
{
    __shared__ float lds[2048];
    const int blk = blockIdx.x;
    const int tid = threadIdx.x;
    const int t8  = tid * 8;

    if (blk < 640) {                       // direct regions (x, W0)
        bf16x8 o;
        if (blk < 512) {                   // x copy
            size_t base = (size_t)blk * 2048 + t8;
            floatx4 a = *(const floatx4*)(x + base);
            floatx4 b = *(const floatx4*)(x + base + 4);
#pragma unroll
            for (int j = 0; j < 4; ++j) { o[j] = (__bf16)a[j]; o[4 + j] = (__bf16)b[j]; }
            *(bf16x8*)(xb + base) = o;
        } else {                           // W0: dst[p_n][c] = W0[invp(p_n)][c] * mask
            long idx = (long)(blk - 512) * 2048 + t8;
            int p_n = (int)(idx >> 7);
            int c   = (int)(idx & 127);
            int dg  = resp_s(p_n);
            const float* s = W0 + (long)invp_s(p_n) * 128 + c;
            floatx4 a = *(const floatx4*)s;
            floatx4 b = *(const floatx4*)(s + 4);
#pragma unroll
            for (int j = 0; j < 8; ++j) {
                float v = j < 4 ? a[j] : b[j - 4];
                o[j] = (__bf16)((dg >= c + j) ? v : 0.0f);
            }
            *(bf16x8*)(w0m + idx) = o;
        }
        return;
    }

    const float* srow; __bf16* drow; int deg_n; bool strict;
    if (blk < 2688) {
        int p_n = blk - 640;
        srow = W1 + (size_t)invp_s(p_n) * 2048; drow = w1m + (size_t)p_n * 2048;
        deg_n = resp_s(p_n); strict = false;
    } else if (blk < 4736) {
        int p_n = blk - 2688;
        srow = W2 + (size_t)invp_s(p_n) * 2048; drow = w2m + (size_t)p_n * 2048;
        deg_n = resp_s(p_n); strict = false;
    } else {
        int n = blk - 4736;
        srow = W3 + (size_t)n * 2048; drow = w3m + (size_t)n * 2048;
        deg_n = n >> 5; strict = true;
    }
    floatx4 a = *(const floatx4*)(srow + t8);
    floatx4 b = *(const floatx4*)(srow + t8 + 4);
    *(floatx4*)&lds[t8]     = a;
    *(floatx4*)&lds[t8 + 4] = b;
    __syncthreads();
    bf16x8 o;
#pragma unroll
    for (int j = 0; j < 8; ++j) {
        int p = t8 + j;
        float v = lds[invp_s(p)];
        int dg = resp_s(p);
        bool keep = strict ? (deg_n > dg) : (deg_n >= dg);
        o[j] = (__bf16)(keep ? v : 0.0f);
    }
    *(bf16x8*)(drow + t8) = o;
}

// ---------------------------------------------------------------------------
// bf16 MFMA GEMM, BK=64, 32x32x16 MFMA (2x2 tiles of 32 per 64x64 wave tile).
// Swizzle: LDS[row][s] = global[row][ s ^ pi(row) ], pi(row)=(row&7)^((row>>3)&3).
// K-prefix skip per LMODE (exact, no tail). LPT bn order. TLAYOUT/PERMBIAS as R9.
// ---------------------------------------------------------------------------
template <bool RELU, bool OBF16, bool TLAYOUT, bool PERMBIAS, int LMODE>
__global__ __launch_bounds__(256, 4)
void gemm_bt(const __bf16* __restrict__ A, const __bf16* __restrict__ Bw,
             const float* __restrict__ bias, void* __restrict__ Cout,
             int N, int K)
{
    __shared__ __align__(16) __bf16 lsA[128 * 64];   // 16 KB
    __shared__ __align__(16) __bf16 lsB[128 * 64];   // 16 KB
    const int tid  = threadIdx.x;
    const int wave = tid >> 6;
    const int lane = tid & 63;
    const int bm = blockIdx.x;
    const int bn = (gridDim.y - 1) - blockIdx.y;     // LPT order
    const int wm = wave >> 1, wn = wave & 1;

    // staging: 32 chunks of 1KB (A:0..15, B:16..31), 8 per wave.
    // chunk j rows [8j,8j+8); lane l -> row 8j+(l>>3), LDS slot l&7;
    // source col-block cb = (l&7) ^ (l>>3) ^ (j&3)  (= slot ^ pi(row))
    const int r8 = lane >> 3;
    const __bf16* gsrc[8];
    __bf16* ldst[8];
#pragma unroll
    for (int t = 0; t < 8; ++t) {
        int j = wave * 8 + t;
        if (j < 16) {
            int row = bm * 128 + j * 8 + r8;
            int cb = (lane & 7) ^ r8 ^ (j & 3);
            gsrc[t] = A + (size_t)row * K + cb * 8;
            ldst[t] = lsA + j * 512;
        } else {
            int jj = j - 16;
            int row = bn * 128 + jj * 8 + r8;
            int cb = (lane & 7) ^ r8 ^ (jj & 3);
            gsrc[t] = Bw + (size_t)row * K + cb * 8;
            ldst[t] = lsB + jj * 512;
        }
    }

    // frag reads (32x32x16): m = lane&31, k = (lane>>5)*8 + j
    const int fr = lane & 31;
    const int kg = lane >> 5;
    const int sw = (fr & 7) ^ (fr >> 3);
    int off[4];
#pragma unroll
    for (int t = 0; t < 4; ++t) off[t] = ((t * 2 + kg) ^ sw) * 8;
    const __bf16* arow[2];
    const __bf16* brow[2];
#pragma unroll
    for (int i = 0; i < 2; ++i) {
        arow[i] = lsA + (wm * 64 + i * 32 + fr) * 64;
        brow[i] = lsB + (wn * 64 + i * 32 + fr) * 64;
    }

    floatx16 acc[2][2];
#pragma unroll
    for (int mi = 0; mi < 2; ++mi)
#pragma unroll
        for (int ni = 0; ni < 2; ++ni)
#pragma unroll
            for (int q = 0; q < 16; ++q) acc[mi][ni][q] = 0.f;

    const int nk = K >> 6;
    int limit;
    if (LMODE == 0)      limit = (cnt_le(resp_s(bn * 128 + 127)) + 63) >> 6;
    else if (LMODE == 1) { int D = 4 * bn + 2; if (D > 126) D = 126;
                           limit = (cnt_le(D) + 63) >> 6; }
    else                 limit = (resp_s(bn * 128 + 127) + 64) >> 6;
    if (limit > nk) limit = nk;

    for (int it = 0; it < limit; ++it) {
        const int kt = it << 6;
        __syncthreads();
#pragma unroll
        for (int t = 0; t < 8; ++t)
            load_lds16((const void*)(gsrc[t] + kt), (void*)ldst[t]);
        __syncthreads();
#pragma unroll
        for (int t = 0; t < 4; ++t) {
            bf16x8 a0 = *(const bf16x8*)(arow[0] + off[t]);
            bf16x8 a1 = *(const bf16x8*)(arow[1] + off[t]);
            bf16x8 b0 = *(const bf16x8*)(brow[0] + off[t]);
            bf16x8 b1 = *(const bf16x8*)(brow[1] + off[t]);
            acc[0][0] = __builtin_amdgcn_mfma_f32_32x32x16_bf16(a0, b0, acc[0][0], 0, 0, 0);
            acc[0][1] = __builtin_amdgcn_mfma_f32_32x32x16_bf16(a0, b1, acc[0][1], 0, 0, 0);
            acc[1][0] = __builtin_amdgcn_mfma_f32_32x32x16_bf16(a1, b0, acc[1][0], 0, 0, 0);
            acc[1][1] = __builtin_amdgcn_mfma_f32_32x32x16_bf16(a1, b1, acc[1][1], 0, 0, 0);
        }
    }

    // epilogue. C/D (32x32): col = lane&31, row = (reg&3) + 8*(reg>>2) + 4*(lane>>5)
    const int cn  = lane & 31;
    const int rhi = (lane >> 5) * 4;
#pragma unroll
    for (int ni = 0; ni < 2; ++ni) {
        int col = bn * 128 + wn * 64 + ni * 32 + cn;
        float bv = bias[PERMBIAS ? invp_s(col) : col];
#pragma unroll
        for (int mi = 0; mi < 2; ++mi) {
#pragma unroll
            for (int qg = 0; qg < 4; ++qg) {
                int rowf = qg * 8 + rhi;                 // rows rowf..rowf+3
                if (TLAYOUT) {
                    size_t addr = (size_t)(bm * 2 + wm) * ((size_t)N * 64)
                                + (size_t)col * 64 + (mi * 32 + rowf);
                    bf16x4 o;
#pragma unroll
                    for (int k = 0; k < 4; ++k) o[k] = (__bf16)(acc[mi][ni][qg * 4 + k] + bv);
                    *(bf16x4*)((__bf16*)Cout + addr) = o;
                } else {
                    int row0 = bm * 128 + wm * 64 + mi * 32 + rowf;
#pragma unroll
                    for (int k = 0; k < 4; ++k) {
                        float v = acc[mi][ni][qg * 4 + k] + bv;
                        if (RELU) v = fmaxf(v, 0.f);
                        if (OBF16) ((__bf16*)Cout)[(size_t)(row0 + k) * N + col] = (__bf16)v;
                        else       ((float*)Cout)[(size_t)(row0 + k) * N + col] = v;
                    }
                }
            }
        }
    }
}

// ---------------------------------------------------------------------------
// Fused log-semiring chain: 126 steps = 14 segs x 9; block = 32 batches x
// 14 seg-waves (448 thr). Segments in registers -> LDS -> in-block pair-tree
// fold + boundaries. theta (bf16) batch-interleaved th2[b>>6][f][b&63].
// ---------------------------------------------------------------------------
__global__ __launch_bounds__(448)
void chain_all(const __bf16* __restrict__ th2,  // [128][4096][64] bf16
               const float* __restrict__ x,     // [8192,128]
               float* __restrict__ out)         // [8192]
{
    __shared__ float xs[32 * 129];               // 16.5 KB (pad 129: no conflicts)
    __shared__ float Pl[32 * 238];               // 29.8 KB: [bl][s*17 + e]
    const int tid = threadIdx.x;
    const int blk = blockIdx.x;                  // 0..255

    for (int idx = tid; idx < 4096; idx += 448) {
        int bl = idx >> 7, i = idx & 127;
        xs[bl * 129 + i] = x[(size_t)blk * 4096 + idx];
    }
    __syncthreads();

    const int s  = tid >> 5;                     // 0..13 (wave-pair uniform)
    const int bl = tid & 31;
    const int b64 = (blk & 1) * 32 + bl;
    const __bf16* tb = th2 + (size_t)(blk >> 1) * (4096 * 64) + b64;

    {   // segment product: 9 steps from i0
        const int i0 = 1 + s * 9;
        const __bf16* tp = tb + (size_t)i0 * 32 * 64;
        float M[4][4];
#pragma unroll
        for (int r = 0; r < 4; ++r)
#pragma unroll
            for (int c = 0; c < 4; ++c) M[r][c] = (r == c) ? 0.f : -1e30f;

        for (int ii = 0; ii < 9; ++ii) {
            float mu[16], al[16];
#pragma unroll
            for (int j = 0; j < 16; ++j) mu[j] = (float)tp[(size_t)j * 64];
#pragma unroll
            for (int j = 0; j < 16; ++j) al[j] = (float)tp[(size_t)(16 + j) * 64];
            float xv = xs[bl * 129 + i0 + ii];
            tp += 2048;                          // 32*64
            float lp[16];
#pragma unroll
            for (int j = 0; j < 16; ++j) lp[j] = logp2(xv, mu[j], al[j]);
            float Mn[4][4];
#pragma unroll
            for (int r = 0; r < 4; ++r)
#pragma unroll
                for (int c = 0; c < 4; ++c)
                    Mn[r][c] = lse4(M[r][0] + lp[0 + c], M[r][1] + lp[4 + c],
                                    M[r][2] + lp[8 + c], M[r][3] + lp[12 + c]);
#pragma unroll
            for (int r = 0; r < 4; ++r)
#pragma unroll
                for (int c = 0; c < 4; ++c) M[r][c] = Mn[r][c];
        }
        float* pb = Pl + bl * 238 + s * 17;
#pragma unroll
        for (int r = 0; r < 4; ++r)
#pragma unroll
            for (int c = 0; c < 4; ++c) pb[r * 4 + c] = M[r][c];
    }
    __syncthreads();

    // fold level 1: 7 pair-products per batch (threads 0..223, j = tid>>5)
    float Q[16];
    if (tid < 224) {
        const float* base = Pl + bl * 238;
        lmm4(base + (2 * s) * 17, base + (2 * s + 1) * 17, Q);
    }
    __syncthreads();
    if (tid < 224) {
        float* dst = Pl + bl * 238 + s * 17;
#pragma unroll
        for (int e = 0; e < 16; ++e) dst[e] = Q[e];
    }
    __syncthreads();

    // fold level 2 + boundaries: one thread per batch (lanes 0..31 of wave 0)
    if (tid < 32) {
        const float* base = Pl + tid * 238;
        float M[16], T[16];
#pragma unroll
        for (int e = 0; e < 16; ++e) M[e] = base[e];
#pragma unroll
        for (int j = 1; j < 7; ++j) {
            lmm4(M, base + j * 17, T);
#pragma unroll
            for (int e = 0; e < 16; ++e) M[e] = T[e];
        }
        const int bb64 = (blk & 1) * 32 + tid;
        const __bf16* tbb = th2 + (size_t)(blk >> 1) * (4096 * 64) + bb64;
        float x0 = xs[tid * 129 + 0];
        float xl = xs[tid * 129 + 127];
        float last[4], t4[4], f4[4];
#pragma unroll
        for (int c = 0; c < 4; ++c)
            last[c] = logp2(xl, (float)tbb[(size_t)(4064 + c * 4) * 64],
                                (float)tbb[(size_t)(4064 + 16 + c * 4) * 64]);
#pragma unroll
        for (int r = 0; r < 4; ++r)
            t4[r] = lse4(M[r * 4 + 0] + last[0], M[r * 4 + 1] + last[1],
                         M[r * 4 + 2] + last[2], M[r * 4 + 3] + last[3]);
#pragma unroll
        for (int r = 0; r < 4; ++r)
            f4[r] = logp2(x0, (float)tbb[(size_t)r * 64],
                              (float)tbb[(size_t)(16 + r) * 64]);
        out[blk * 32 + tid] = LN2 * lse4(f4[0] + t4[0], f4[1] + t4[1],
                                         f4[2] + t4[2], f4[3] + t4[3]);
    }
}

// ---------------------------------------------------------------------------
extern "C" void kernel_launch(void* const* d_in, const int* in_sizes, int n_in,
                              void* d_out, int out_size, void* d_ws, size_t ws_size,
                              hipStream_t stream)
{
    (void)in_sizes; (void)n_in; (void)out_size; (void)ws_size;
    const float* x  = (const float*)d_in[0];
    const float* W0 = (const float*)d_in[1];
    const float* b0 = (const float*)d_in[2];
    const float* W1 = (const float*)d_in[3];
    const float* b1 = (const float*)d_in[4];
    const float* W2 = (const float*)d_in[5];
    const float* b2 = (const float*)d_in[6];
    const float* W3 = (const float*)d_in[7];
    const float* b3 = (const float*)d_in[8];

    // Compact arena (112 MB): th overlays regions dead before GEMM3.
    char* ws = (char*)d_ws;
    const size_t MB = 1024 * 1024;
    __bf16* h2  = (__bf16*)(ws + 0);          // 32 MB: g1 out, g2 in; dead after g2
    __bf16* xb  = (__bf16*)(ws + 32 * MB);    // 2 MB:  prep -> g0
    __bf16* w0m = (__bf16*)(ws + 34 * MB);    // 0.5MB: prep -> g0
    __bf16* w1m = (__bf16*)(ws + 35 * MB);    // 8 MB:  prep -> g1
    __bf16* w2m = (__bf16*)(ws + 43 * MB);    // 8 MB:  prep -> g2
    __bf16* th  = (__bf16*)(ws + 0);          // 64 MB: g3 out (overlays the above)
    __bf16* w3m = (__bf16*)(ws + 64 * MB);    // 16 MB: prep -> g3 (not overlaid)
    __bf16* h1  = (__bf16*)(ws + 80 * MB);    // 32 MB: g0 out; g2 writes h3=h1; g3 in
    __bf16* h3  = h1;

    prep_all<<<8832, 256, 0, stream>>>(x, W0, W1, W2, W3, xb, w0m, w1m, w2m, w3m);

    // GEMM0: sorted N, natural K=128 (LMODE 2)
    gemm_bt<true, true, false, true, 2><<<dim3(64, 16), 256, 0, stream>>>(
        xb, w0m, b0, h1, 2048, 128);
    // GEMM1/2: sorted N, sorted K (LMODE 0)
    gemm_bt<true, true, false, true, 0><<<dim3(64, 16), 256, 0, stream>>>(
        h1, w1m, b1, h2, 2048, 2048);
    gemm_bt<true, true, false, true, 0><<<dim3(64, 16), 256, 0, stream>>>(
        h2, w2m, b2, h3, 2048, 2048);
    // GEMM3: natural N, sorted K (LMODE 1), theta bf16 TLAYOUT store
    gemm_bt<false, false, true, false, 1><<<dim3(64, 32), 256, 0, stream>>>(
        h3, w3m, b3, th, 4096, 2048);

    // fused segment chain + fold (single dispatch)
    chain_all<<<256, 448, 0, stream>>>(th, x, (float*)d_out);
}

// Round 11
// 319.699 us; speedup vs baseline: 1.0456x; 1.0456x over previous
//
#include <hip/hip_runtime.h>
#include <hip/hip_bf16.h>
#include <cstdint>
#include <cstddef>

#define AS1 __attribute__((address_space(1)))
#define AS3 __attribute__((address_space(3)))

typedef __bf16 bf16x8  __attribute__((ext_vector_type(8)));
typedef float  floatx4 __attribute__((ext_vector_type(4)));

__device__ __forceinline__ void load_lds16(const void* g, void* l) {
    __builtin_amdgcn_global_load_lds((AS1 void*)g, (AS3 void*)l, 16, 0, 0);
}

__device__ __forceinline__ float fexp2(float x) { return __builtin_amdgcn_exp2f(x); }
__device__ __forceinline__ float flog2(float x) { return __builtin_amdgcn_logf(x); }

#define LOG2E 1.4426950408889634f
#define LN2   0.6931471805599453f
#define C0K   2.3052328943245633f   /* 0.5*log(2pi) + log(4) */

__device__ __forceinline__ float logp2(float xv, float mu, float al) {
    float e = fexp2(-al * LOG2E);
    float z = (xv - mu) * e;
    return (-0.5f * z * z - al - C0K) * LOG2E;
}
__device__ __forceinline__ float lse4(float a0, float a1, float a2, float a3) {
    float mx = fmaxf(fmaxf(a0, a1), fmaxf(a2, a3));
    return mx + flog2(fexp2(a0 - mx) + fexp2(a1 - mx) +
                      fexp2(a2 - mx) + fexp2(a3 - mx));
}
__device__ __forceinline__ void lmm4(const float* Aa, const float* Bb, float* D) {
#pragma unroll
    for (int r = 0; r < 4; ++r)
#pragma unroll
        for (int c = 0; c < 4; ++c)
            D[r * 4 + c] = lse4(Aa[r * 4 + 0] + Bb[0 * 4 + c],
                                Aa[r * 4 + 1] + Bb[1 * 4 + c],
                                Aa[r * 4 + 2] + Bb[2 * 4 + c],
                                Aa[r * 4 + 3] + Bb[3 * 4 + c]);
}

// EXACT degree sort of the 2048 hidden features, deg(f) = f % 127.
__device__ __forceinline__ int resp_s(int p) {
    return p < 272 ? p / 17 : 16 + ((p - 272) >> 4);
}
__device__ __forceinline__ int invp_s(int p) {
    if (p < 272) { int d = p / 17; int r = p - d * 17;
                   return r < 16 ? d + r * 127 : 2032 + d; }
    int d = 16 + ((p - 272) >> 4); int j = (p - 272) & 15;
    return d + j * 127;
}
__device__ __forceinline__ int cnt_le(int D) {
    return D < 16 ? (D + 1) * 17 : 272 + ((D - 15) << 4);
}

// ---------------------------------------------------------------------------
// Prep: masks + fp32->bf16 + exact degree-sort, coalesced both sides via LDS.
// ---------------------------------------------------------------------------
__global__ __launch_bounds__(256)
void prep_all(const float* __restrict__ x,  const float* __restrict__ W0,
              const float* __restrict__ W1, const float* __restrict__ W2,
              const float* __restrict__ W3,
              __bf16* __restrict__ xb,  __bf16* __restrict__ w0m,
              __bf16* __restrict__ w1m, __bf16* __restrict__ w2m,
              __bf16* __restrict__ w3m)
{
    __shared__ float lds[2048];
    const int blk = blockIdx.x;
    const int tid = threadIdx.x;
    const int t8  = tid * 8;

    if (blk < 640) {                       // direct regions (x, W0)
        bf16x8 o;
        if (blk < 512) {                   // x copy
            size_t base = (size_t)blk * 2048 + t8;
            floatx4 a = *(const floatx4*)(x + base);
            floatx4 b = *(const floatx4*)(x + base + 4);
#pragma unroll
            for (int j = 0; j < 4; ++j) { o[j] = (__bf16)a[j]; o[4 + j] = (__bf16)b[j]; }
            *(bf16x8*)(xb + base) = o;
        } else {                           // W0: dst[p_n][c] = W0[invp(p_n)][c] * mask
            long idx = (long)(blk - 512) * 2048 + t8;
            int p_n = (int)(idx >> 7);
            int c   = (int)(idx & 127);
            int dg  = resp_s(p_n);
            const float* s = W0 + (long)invp_s(p_n) * 128 + c;
            floatx4 a = *(const floatx4*)s;
            floatx4 b = *(const floatx4*)(s + 4);
#pragma unroll
            for (int j = 0; j < 8; ++j) {
                float v = j < 4 ? a[j] : b[j - 4];
                o[j] = (__bf16)((dg >= c + j) ? v : 0.0f);
            }
            *(bf16x8*)(w0m + idx) = o;
        }
        return;
    }

    const float* srow; __bf16* drow; int deg_n; bool strict;
    if (blk < 2688) {
        int p_n = blk - 640;
        srow = W1 + (size_t)invp_s(p_n) * 2048; drow = w1m + (size_t)p_n * 2048;
        deg_n = resp_s(p_n); strict = false;
    } else if (blk < 4736) {
        int p_n = blk - 2688;
        srow = W2 + (size_t)invp_s(p_n) * 2048; drow = w2m + (size_t)p_n * 2048;
        deg_n = resp_s(p_n); strict = false;
    } else {
        int n = blk - 4736;
        srow = W3 + (size_t)n * 2048; drow = w3m + (size_t)n * 2048;
        deg_n = n >> 5; strict = true;
    }
    floatx4 a = *(const floatx4*)(srow + t8);
    floatx4 b = *(const floatx4*)(srow + t8 + 4);
    *(floatx4*)&lds[t8]     = a;
    *(floatx4*)&lds[t8 + 4] = b;
    __syncthreads();
    bf16x8 o;
#pragma unroll
    for (int j = 0; j < 8; ++j) {
        int p = t8 + j;
        float v = lds[invp_s(p)];
        int dg = resp_s(p);
        bool keep = strict ? (deg_n > dg) : (deg_n >= dg);
        o[j] = (__bf16)(keep ? v : 0.0f);
    }
    *(bf16x8*)(drow + t8) = o;
}

// ---------------------------------------------------------------------------
// bf16 MFMA GEMM, BK=64, 16x16x32 MFMA 4x4/wave (R9-proven K-loop).
// Exact K-prefix skip per LMODE. LPT bn order. TLAYOUT/PERMBIAS as before.
// ---------------------------------------------------------------------------
template <bool RELU, bool OBF16, bool TLAYOUT, bool PERMBIAS, int LMODE>
__global__ __launch_bounds__(256, 4)
void gemm_bt(const __bf16* __restrict__ A, const __bf16* __restrict__ Bw,
             const float* __restrict__ bias, void* __restrict__ Cout,
             int N, int K)
{
    __shared__ __align__(16) __bf16 lsA[128 * 64];   // 16 KB
    __shared__ __align__(16) __bf16 lsB[128 * 64];   // 16 KB
    const int tid  = threadIdx.x;
    const int wave = tid >> 6;
    const int lane = tid & 63;
    const int bm = blockIdx.x;
    const int bn = (gridDim.y - 1) - blockIdx.y;     // LPT order
    const int wm = wave >> 1, wn = wave & 1;

    // staging: 32 chunks of 1KB (A:0..15, B:16..31), 8 per wave.
    // chunk j covers rows [8j,8j+8); DMA puts lane l at LDS slot (l&7), so we
    // read global col-block (l&7)^(l>>3) -> LDS[row][s] = global[row][s^(row&7)]
    const int r8 = lane >> 3;
    const int cb = (lane & 7) ^ r8;
    const __bf16* gsrc[8];
    __bf16* ldst[8];
#pragma unroll
    for (int t = 0; t < 8; ++t) {
        int j = wave * 8 + t;
        if (j < 16) {
            int row = bm * 128 + j * 8 + r8;
            gsrc[t] = A + (size_t)row * K + cb * 8;
            ldst[t] = lsA + j * 512;
        } else {
            int jj = j - 16;
            int row = bn * 128 + jj * 8 + r8;
            gsrc[t] = Bw + (size_t)row * K + cb * 8;
            ldst[t] = lsB + jj * 512;
        }
    }

    // frag reads: row fr, global k-block g=kk*4+ks lives at LDS slot g^(fr&7)
    const int fr  = lane & 15;
    const int ks  = lane >> 4;
    const int sx  = fr & 7;
    const int sl0 = ((ks)     ^ sx) * 8;
    const int sl1 = ((4 + ks) ^ sx) * 8;
    const __bf16* arow[4];
    const __bf16* brow[4];
#pragma unroll
    for (int i = 0; i < 4; ++i) {
        arow[i] = lsA + (wm * 64 + i * 16 + fr) * 64;
        brow[i] = lsB + (wn * 64 + i * 16 + fr) * 64;
    }

    floatx4 acc[4][4];
    const floatx4 vzero = {0.f, 0.f, 0.f, 0.f};
#pragma unroll
    for (int mi = 0; mi < 4; ++mi)
#pragma unroll
        for (int ni = 0; ni < 4; ++ni) acc[mi][ni] = vzero;

    const int nk = K >> 6;
    int limit;
    if (LMODE == 0)      limit = (cnt_le(resp_s(bn * 128 + 127)) + 63) >> 6;
    else if (LMODE == 1) { int D = 4 * bn + 2; if (D > 126) D = 126;
                           limit = (cnt_le(D) + 63) >> 6; }
    else                 limit = (resp_s(bn * 128 + 127) + 64) >> 6;
    if (limit > nk) limit = nk;

    for (int it = 0; it < limit; ++it) {
        const int kt = it << 6;
        __syncthreads();
#pragma unroll
        for (int t = 0; t < 8; ++t)
            load_lds16((const void*)(gsrc[t] + kt), (void*)ldst[t]);
        __syncthreads();
        bf16x8 af[4], bf[4];
#pragma unroll
        for (int i = 0; i < 4; ++i) af[i] = *(const bf16x8*)(arow[i] + sl0);
#pragma unroll
        for (int i = 0; i < 4; ++i) bf[i] = *(const bf16x8*)(brow[i] + sl0);
#pragma unroll
        for (int mi = 0; mi < 4; ++mi)
#pragma unroll
            for (int ni = 0; ni < 4; ++ni)
                acc[mi][ni] = __builtin_amdgcn_mfma_f32_16x16x32_bf16(
                    af[mi], bf[ni], acc[mi][ni], 0, 0, 0);
#pragma unroll
        for (int i = 0; i < 4; ++i) af[i] = *(const bf16x8*)(arow[i] + sl1);
#pragma unroll
        for (int i = 0; i < 4; ++i) bf[i] = *(const bf16x8*)(brow[i] + sl1);
#pragma unroll
        for (int mi = 0; mi < 4; ++mi)
#pragma unroll
            for (int ni = 0; ni < 4; ++ni)
                acc[mi][ni] = __builtin_amdgcn_mfma_f32_16x16x32_bf16(
                    af[mi], bf[ni], acc[mi][ni], 0, 0, 0);
    }

    const int cn  = lane & 15;
    const int cr4 = (lane >> 4) * 4;
#pragma unroll
    for (int ni = 0; ni < 4; ++ni) {
        int col = bn * 128 + wn * 64 + ni * 16 + cn;
        float bv = bias[PERMBIAS ? invp_s(col) : col];
#pragma unroll
        for (int mi = 0; mi < 4; ++mi) {
            int row0 = bm * 128 + wm * 64 + mi * 16 + cr4;
#pragma unroll
            for (int q = 0; q < 4; ++q) {
                float v = acc[mi][ni][q] + bv;
                if (RELU) v = fmaxf(v, 0.f);
                if (TLAYOUT) {
                    // b = row0+q; b>>6 = bm*2+wm; b&63 = mi*16+cr4+q
                    size_t addr = (size_t)(bm * 2 + wm) * ((size_t)N * 64)
                                + (size_t)col * 64 + (mi * 16 + cr4 + q);
                    ((__bf16*)Cout)[addr] = (__bf16)v;
                } else if (OBF16) {
                    ((__bf16*)Cout)[(size_t)(row0 + q) * N + col] = (__bf16)v;
                } else {
                    ((float*)Cout)[(size_t)(row0 + q) * N + col] = v;
                }
            }
        }
    }
}

// ---------------------------------------------------------------------------
// Fused log-semiring chain: 126 steps = 14 segs x 9; block = 32 batches x
// 14 seg-waves (448 thr). Segments in registers -> LDS -> in-block pair-tree
// fold + boundaries. theta (bf16) batch-interleaved th2[b>>6][f][b&63].
// ---------------------------------------------------------------------------
__global__ __launch_bounds__(448)
void chain_all(const __bf16* __restrict__ th2,  // [128][4096][64] bf16
               const float* __restrict__ x,     // [8192,128]
               float* __restrict__ out)         // [8192]
{
    __shared__ float xs[32 * 129];               // 16.5 KB (pad 129: no conflicts)
    __shared__ float Pl[32 * 238];               // 29.8 KB: [bl][s*17 + e]
    const int tid = threadIdx.x;
    const int blk = blockIdx.x;                  // 0..255

    for (int idx = tid; idx < 4096; idx += 448) {
        int bl = idx >> 7, i = idx & 127;
        xs[bl * 129 + i] = x[(size_t)blk * 4096 + idx];
    }
    __syncthreads();

    const int s  = tid >> 5;                     // 0..13
    const int bl = tid & 31;
    const int b64 = (blk & 1) * 32 + bl;
    const __bf16* tb = th2 + (size_t)(blk >> 1) * (4096 * 64) + b64;

    {   // segment product: 9 steps from i0
        const int i0 = 1 + s * 9;
        const __bf16* tp = tb + (size_t)i0 * 32 * 64;
        float M[4][4];
#pragma unroll
        for (int r = 0; r < 4; ++r)
#pragma unroll
            for (int c = 0; c < 4; ++c) M[r][c] = (r == c) ? 0.f : -1e30f;

        for (int ii = 0; ii < 9; ++ii) {
            float mu[16], al[16];
#pragma unroll
            for (int j = 0; j < 16; ++j) mu[j] = (float)tp[(size_t)j * 64];
#pragma unroll
            for (int j = 0; j < 16; ++j) al[j] = (float)tp[(size_t)(16 + j) * 64];
            float xv = xs[bl * 129 + i0 + ii];
            tp += 2048;                          // 32*64
            float lp[16];
#pragma unroll
            for (int j = 0; j < 16; ++j) lp[j] = logp2(xv, mu[j], al[j]);
            float Mn[4][4];
#pragma unroll
            for (int r = 0; r < 4; ++r)
#pragma unroll
                for (int c = 0; c < 4; ++c)
                    Mn[r][c] = lse4(M[r][0] + lp[0 + c], M[r][1] + lp[4 + c],
                                    M[r][2] + lp[8 + c], M[r][3] + lp[12 + c]);
#pragma unroll
            for (int r = 0; r < 4; ++r)
#pragma unroll
                for (int c = 0; c < 4; ++c) M[r][c] = Mn[r][c];
        }
        float* pb = Pl + bl * 238 + s * 17;
#pragma unroll
        for (int r = 0; r < 4; ++r)
#pragma unroll
            for (int c = 0; c < 4; ++c) pb[r * 4 + c] = M[r][c];
    }
    __syncthreads();

    // fold level 1: 7 pair-products per batch (threads 0..223)
    float Q[16];
    if (tid < 224) {
        const float* base = Pl + bl * 238;
        lmm4(base + (2 * s) * 17, base + (2 * s + 1) * 17, Q);
    }
    __syncthreads();
    if (tid < 224) {
        float* dst = Pl + bl * 238 + s * 17;
#pragma unroll
        for (int e = 0; e < 16; ++e) dst[e] = Q[e];
    }
    __syncthreads();

    // fold level 2 + boundaries: one thread per batch
    if (tid < 32) {
        const float* base = Pl + tid * 238;
        float M[16], T[16];
#pragma unroll
        for (int e = 0; e < 16; ++e) M[e] = base[e];
#pragma unroll
        for (int j = 1; j < 7; ++j) {
            lmm4(M, base + j * 17, T);
#pragma unroll
            for (int e = 0; e < 16; ++e) M[e] = T[e];
        }
        const int bb64 = (blk & 1) * 32 + tid;
        const __bf16* tbb = th2 + (size_t)(blk >> 1) * (4096 * 64) + bb64;
        float x0 = xs[tid * 129 + 0];
        float xl = xs[tid * 129 + 127];
        float last[4], t4[4], f4[4];
#pragma unroll
        for (int c = 0; c < 4; ++c)
            last[c] = logp2(xl, (float)tbb[(size_t)(4064 + c * 4) * 64],
                                (float)tbb[(size_t)(4064 + 16 + c * 4) * 64]);
#pragma unroll
        for (int r = 0; r < 4; ++r)
            t4[r] = lse4(M[r * 4 + 0] + last[0], M[r * 4 + 1] + last[1],
                         M[r * 4 + 2] + last[2], M[r * 4 + 3] + last[3]);
#pragma unroll
        for (int r = 0; r < 4; ++r)
            f4[r] = logp2(x0, (float)tbb[(size_t)r * 64],
                              (float)tbb[(size_t)(16 + r) * 64]);
        out[blk * 32 + tid] = LN2 * lse4(f4[0] + t4[0], f4[1] + t4[1],
                                         f4[2] + t4[2], f4[3] + t4[3]);
    }
}

// ---------------------------------------------------------------------------
extern "C" void kernel_launch(void* const* d_in, const int* in_sizes, int n_in,
                              void* d_out, int out_size, void* d_ws, size_t ws_size,
                              hipStream_t stream)
{
    (void)in_sizes; (void)n_in; (void)out_size; (void)ws_size;
    const float* x  = (const float*)d_in[0];
    const float* W0 = (const float*)d_in[1];
    const float* b0 = (const float*)d_in[2];
    const float* W1 = (const float*)d_in[3];
    const float* b1 = (const float*)d_in[4];
    const float* W2 = (const float*)d_in[5];
    const float* b2 = (const float*)d_in[6];
    const float* W3 = (const float*)d_in[7];
    const float* b3 = (const float*)d_in[8];

    // Compact arena (112 MB): th overlays regions dead before GEMM3.
    char* ws = (char*)d_ws;
    const size_t MB = 1024 * 1024;
    __bf16* h2  = (__bf16*)(ws + 0);          // 32 MB: g1 out, g2 in; dead after g2
    __bf16* xb  = (__bf16*)(ws + 32 * MB);    // 2 MB:  prep -> g0
    __bf16* w0m = (__bf16*)(ws + 34 * MB);    // 0.5MB: prep -> g0
    __bf16* w1m = (__bf16*)(ws + 35 * MB);    // 8 MB:  prep -> g1
    __bf16* w2m = (__bf16*)(ws + 43 * MB);    // 8 MB:  prep -> g2
    __bf16* th  = (__bf16*)(ws + 0);          // 64 MB: g3 out (overlays the above)
    __bf16* w3m = (__bf16*)(ws + 64 * MB);    // 16 MB: prep -> g3 (not overlaid)
    __bf16* h1  = (__bf16*)(ws + 80 * MB);    // 32 MB: g0 out; g2 writes h3=h1; g3 in
    __bf16* h3  = h1;

    prep_all<<<8832, 256, 0, stream>>>(x, W0, W1, W2, W3, xb, w0m, w1m, w2m, w3m);

    // GEMM0: sorted N, natural K=128 (LMODE 2)
    gemm_bt<true, true, false, true, 2><<<dim3(64, 16), 256, 0, stream>>>(
        xb, w0m, b0, h1, 2048, 128);
    // GEMM1/2: sorted N, sorted K (LMODE 0)
    gemm_bt<true, true, false, true, 0><<<dim3(64, 16), 256, 0, stream>>>(
        h1, w1m, b1, h2, 2048, 2048);
    gemm_bt<true, true, false, true, 0><<<dim3(64, 16), 256, 0, stream>>>(
        h2, w2m, b2, h3, 2048, 2048);
    // GEMM3: natural N, sorted K (LMODE 1), theta bf16 TLAYOUT store
    gemm_bt<false, false, true, false, 1><<<dim3(64, 32), 256, 0, stream>>>(
        h3, w3m, b3, th, 4096, 2048);

    // fused segment chain + fold (single dispatch)
    chain_all<<<256, 448, 0, stream>>>(th, x, (float*)d_out);
}